// Round 2
// baseline (518.296 us; speedup 1.0000x reference)
//
#include <hip/hip_runtime.h>
#include <hip/hip_bf16.h>

// WindowAttentionRPB fused kernel v2, MI355X gfx950.
// 1 block = 1 window, 512 threads = 8 waves = 8 heads.
// LDS 64K: x bf16 [64][256] at 32K..64K (overlays waves4-7 scratch);
// per-wave 8K scratch (slot0/slot1, sequentially reused q->vT, k->P-chunks);
// attn-shared [64][256] at 0..32K (overlays waves0-3 scratch, after barrier).
// 2 blocks/CU target (launch_bounds(512,4), VGPR<=128).
// rpb+mask via pre-permuted float4 tables [qtok][ll*4+ni].

#define TOK 64
#define CDIM 256
#define XOFF 32768

typedef __attribute__((ext_vector_type(8))) short short8;
typedef __attribute__((ext_vector_type(4))) float f32x4;
typedef __attribute__((ext_vector_type(4))) float float4_t;

__device__ __forceinline__ short f2bf(float f) {
  union { float f; unsigned u; } v; v.f = f;
  unsigned r = v.u + 0x7FFFu + ((v.u >> 16) & 1u);
  return (short)(r >> 16);
}

// swizzled byte address into a row-major [64][256] bf16 LDS region
__device__ __forceinline__ int rm_addr(int base, int row, int col) {
  return base + row * 512 + ((col * 2) ^ ((row & 7) << 4));
}

__global__ void preconv_kernel(const float* __restrict__ qkv_w,
                               const float* __restrict__ proj_w,
                               const float* __restrict__ rpb_table,
                               const int* __restrict__ rpb_index,
                               const float* __restrict__ mask,
                               short* __restrict__ wqkv,
                               short* __restrict__ wproj,
                               float* __restrict__ rpbT,
                               float* __restrict__ maskT) {
  int idx = blockIdx.x * blockDim.x + threadIdx.x;
  const float scale = 0.17677669529663687f; // 1/sqrt(32), folded into Wq
  const int NW1 = 768 * 256;            // 196608
  const int NW2 = NW1 + 256 * 256;      // +65536
  const int NW3 = NW2 + 8 * 64 * 64;    // +32768 rpbT
  const int NW4 = NW3 + 64 * 64 * 64;   // +262144 maskT
  if (idx < NW1) {
    float v = qkv_w[idx];
    if (idx < 256 * 256) v *= scale;
    wqkv[idx] = f2bf(v);
  } else if (idx < NW2) {
    int i = idx - NW1;
    wproj[i] = f2bf(proj_w[i]);
  } else if (idx < NW3) {
    int i = idx - NW2;             // [h][qtok][ll*4+ni]
    int h = i >> 12;
    int pos = i & 4095;
    int qtok = pos >> 6;
    int t = pos & 63;
    int llv = t >> 2, ni = t & 3;
    int kt = ni * 16 + llv;
    rpbT[i] = rpb_table[rpb_index[qtok * 64 + kt] * 8 + h];
  } else if (idx < NW4) {
    int i = idx - NW3;             // [win][qtok][ll*4+ni]
    int win = i >> 12;
    int pos = i & 4095;
    int qtok = pos >> 6;
    int t = pos & 63;
    int llv = t >> 2, ni = t & 3;
    int kt = ni * 16 + llv;
    maskT[i] = mask[win * 4096 + qtok * 64 + kt];
  }
}

__global__ void __launch_bounds__(512, 4) fused_attn(
    const float* __restrict__ x, const float* __restrict__ qkv_b,
    const float* __restrict__ proj_b,
    const short* __restrict__ wqkv, const short* __restrict__ wproj,
    const float* __restrict__ rpbT, const float* __restrict__ maskT,
    float* __restrict__ out) {
  extern __shared__ char smem[];
  const int b = blockIdx.x;
  const int tid = threadIdx.x;
  const int w = tid >> 6;      // wave = head
  const int lane = tid & 63;
  const int lg = lane >> 4;    // lane group 0..3
  const int ll = lane & 15;
  const float scale = 0.17677669529663687f;
  const int S0 = w * 8192, S1 = S0 + 4096;

  // ---- stage x -> LDS bf16 swizzled at XOFF ([64][256])
  {
    const int row = tid >> 3;
    const int c0 = (tid & 7) * 32;
    const float4_t* src = reinterpret_cast<const float4_t*>(
        x + (size_t)b * TOK * CDIM + row * CDIM + c0);
    for (int j = 0; j < 4; ++j) {
      float4_t f0 = src[2 * j];
      float4_t f1 = src[2 * j + 1];
      short8 s;
      s[0] = f2bf(f0[0]); s[1] = f2bf(f0[1]); s[2] = f2bf(f0[2]); s[3] = f2bf(f0[3]);
      s[4] = f2bf(f1[0]); s[5] = f2bf(f1[1]); s[6] = f2bf(f1[2]); s[7] = f2bf(f1[3]);
      *reinterpret_cast<short8*>(smem + rm_addr(XOFF, row, c0 + 8 * j)) = s;
    }
  }
  __syncthreads();

  // ---- QKV GEMM: wave w computes head w's q,k,v (64 x 96 cols)
  f32x4 acc[4][6] = {};
  for (int ks = 0; ks < 8; ++ks) {
    int k0 = ks * 32;
    short8 a[4];
    for (int mi = 0; mi < 4; ++mi)
      a[mi] = *reinterpret_cast<const short8*>(
          smem + rm_addr(XOFF, ll + 16 * mi, k0 + lg * 8));
    for (int j = 0; j < 6; ++j) {
      int s = j >> 1, hf = j & 1;
      int c = s * 256 + w * 32 + hf * 16 + ll;
      short8 bb = *reinterpret_cast<const short8*>(wqkv + c * 256 + k0 + lg * 8);
      for (int mi = 0; mi < 4; ++mi)
        acc[mi][j] = __builtin_amdgcn_mfma_f32_16x16x32_bf16(a[mi], bb, acc[mi][j], 0, 0, 0);
    }
  }
  __syncthreads();  // x region dead; scratch (incl. overlay) safe to write

  // ---- q -> slot0, k -> slot1  ([64 tok][32 d], swz (tok&3)<<4)
  for (int j = 0; j < 4; ++j) {
    int s = j >> 1, hf = j & 1;
    int c = s * 256 + w * 32 + hf * 16 + ll;
    float bias = qkv_b[c];
    if (s == 0) bias *= scale;
    int base = (s == 0) ? S0 : S1;
    int dl2 = (hf * 16 + ll) * 2;
    for (int mi = 0; mi < 4; ++mi)
      for (int r = 0; r < 4; ++r) {
        int tok = lg * 4 + r + 16 * mi;
        *reinterpret_cast<short*>(smem + base + tok * 64 + (dl2 ^ ((tok & 3) << 4))) =
            f2bf(acc[mi][j][r] + bias);
      }
  }
  // ---- read Q/K fragments
  short8 aq[4], bk[4];
  for (int mi = 0; mi < 4; ++mi)
    aq[mi] = *reinterpret_cast<const short8*>(
        smem + S0 + (ll + 16 * mi) * 64 + ((lg * 16) ^ (((ll + 16 * mi) & 3) << 4)));
  for (int ni = 0; ni < 4; ++ni)
    bk[ni] = *reinterpret_cast<const short8*>(
        smem + S1 + (ll + 16 * ni) * 64 + ((lg * 16) ^ (((ll + 16 * ni) & 3) << 4)));

  // ---- vT -> slot0 (overlays q; q frags already in regs). [32 d][64 tok]
  for (int hf = 0; hf < 2; ++hf) {
    int c = 2 * 256 + w * 32 + hf * 16 + ll;
    float bias = qkv_b[c];
    int d = hf * 16 + ll;
    for (int mi = 0; mi < 4; ++mi)
      for (int rp = 0; rp < 2; ++rp) {
        int tok0 = lg * 4 + rp * 2 + 16 * mi;
        unsigned u = (unsigned)(unsigned short)f2bf(acc[mi][4 + hf][2 * rp] + bias)
                   | ((unsigned)(unsigned short)f2bf(acc[mi][4 + hf][2 * rp + 1] + bias) << 16);
        *reinterpret_cast<unsigned*>(smem + S0 + d * 128 + ((tok0 * 2) ^ ((d & 7) << 4))) = u;
      }
  }

  // ---- S = q_scaled @ k^T + rpb + mask
  f32x4 sa[4][4];
  {
    f32x4 z{0.0f, 0.0f, 0.0f, 0.0f};
    for (int mi = 0; mi < 4; ++mi)
      for (int ni = 0; ni < 4; ++ni)
        sa[mi][ni] = __builtin_amdgcn_mfma_f32_16x16x32_bf16(aq[mi], bk[ni], z, 0, 0, 0);
    const float4_t* rpT4 = reinterpret_cast<const float4_t*>(rpbT) + w * 1024;
    const float4_t* mkT4 = reinterpret_cast<const float4_t*>(maskT) + (b & 63) * 1024;
    for (int mi = 0; mi < 4; ++mi)
      for (int r = 0; r < 4; ++r) {
        int qtok = lg * 4 + r + 16 * mi;
        float4_t f = rpT4[qtok * 16 + ll];
        float4_t g = mkT4[qtok * 16 + ll];
        for (int ni = 0; ni < 4; ++ni)
          sa[mi][ni][r] += f[ni] + g[ni];
      }
  }

  // ---- softmax over cols (row lives in one 16-lane group)
  float rinv[4][4];
  for (int mi = 0; mi < 4; ++mi)
    for (int r = 0; r < 4; ++r) {
      float m = sa[mi][0][r];
      for (int ni = 1; ni < 4; ++ni) m = fmaxf(m, sa[mi][ni][r]);
      for (int d = 1; d < 16; d <<= 1) m = fmaxf(m, __shfl_xor(m, d));
      float sum = 0.f;
      for (int ni = 0; ni < 4; ++ni) {
        float e = __expf(sa[mi][ni][r] - m);
        sa[mi][ni][r] = e;
        sum += e;
      }
      for (int d = 1; d < 16; d <<= 1) sum += __shfl_xor(sum, d);
      rinv[mi][r] = 1.0f / sum;
    }

  // ---- PV in two 32-kt chunks through slot1 (overlays k)
  f32x4 oa[4][2] = {};
  for (int ks = 0; ks < 2; ++ks) {
    for (int mi = 0; mi < 4; ++mi)
      for (int nio = 0; nio < 2; ++nio) {
        int ni = 2 * ks + nio;
        int ktl2 = (nio * 16 + ll) * 2;
        for (int r = 0; r < 4; ++r) {
          int qtok = lg * 4 + r + 16 * mi;
          *reinterpret_cast<short*>(smem + S1 + qtok * 64 + (ktl2 ^ ((qtok & 3) << 4))) =
              f2bf(sa[mi][ni][r]);
        }
      }
    short8 ap[4], bv[2];
    for (int mi = 0; mi < 4; ++mi)
      ap[mi] = *reinterpret_cast<const short8*>(
          smem + S1 + (ll + 16 * mi) * 64 + ((lg * 16) ^ (((ll + 16 * mi) & 3) << 4)));
    for (int njf = 0; njf < 2; ++njf) {
      int d = njf * 16 + ll;
      bv[njf] = *reinterpret_cast<const short8*>(
          smem + S0 + d * 128 + (((ks * 32 + lg * 8) * 2) ^ ((d & 7) << 4)));
    }
    for (int mi = 0; mi < 4; ++mi)
      for (int njf = 0; njf < 2; ++njf)
        oa[mi][njf] = __builtin_amdgcn_mfma_f32_16x16x32_bf16(ap[mi], bv[njf], oa[mi][njf], 0, 0, 0);
  }

  __syncthreads();  // all scratch reads done -> attn region (0..32K) writable

  // ---- normalize rows, write attn output (bf16) into attn region [64][256]
  for (int mi = 0; mi < 4; ++mi)
    for (int nj = 0; nj < 2; ++nj)
      for (int r = 0; r < 4; ++r) {
        int row = lg * 4 + r + 16 * mi;
        float v = oa[mi][nj][r] * rinv[mi][r];
        *reinterpret_cast<short*>(smem + rm_addr(0, row, w * 32 + nj * 16 + ll)) = f2bf(v);
      }
  __syncthreads();

  // ---- proj GEMM: out[64][256] = attn[64][256] @ Wp^T + bias
  f32x4 pa[4][2] = {};
  for (int ks = 0; ks < 8; ++ks) {
    int k0 = ks * 32;
    short8 a[4];
    for (int mi = 0; mi < 4; ++mi)
      a[mi] = *reinterpret_cast<const short8*>(
          smem + rm_addr(0, ll + 16 * mi, k0 + lg * 8));
    for (int nj = 0; nj < 2; ++nj) {
      int c = w * 32 + nj * 16 + ll;
      short8 bb = *reinterpret_cast<const short8*>(wproj + c * 256 + k0 + lg * 8);
      for (int mi = 0; mi < 4; ++mi)
        pa[mi][nj] = __builtin_amdgcn_mfma_f32_16x16x32_bf16(a[mi], bb, pa[mi][nj], 0, 0, 0);
    }
  }
  float* outp = out + (size_t)b * TOK * CDIM;
  for (int nj = 0; nj < 2; ++nj) {
    int c = w * 32 + nj * 16 + ll;
    float bias = proj_b[c];
    for (int mi = 0; mi < 4; ++mi)
      for (int r = 0; r < 4; ++r) {
        int row = lg * 4 + r + 16 * mi;
        outp[row * 256 + c] = pa[mi][nj][r] + bias;
      }
  }
}

extern "C" void kernel_launch(void* const* d_in, const int* in_sizes, int n_in,
                              void* d_out, int out_size, void* d_ws, size_t ws_size,
                              hipStream_t stream) {
  const float* x        = (const float*)d_in[0];
  const float* mask     = (const float*)d_in[1];
  const float* qkv_w    = (const float*)d_in[2];
  const float* qkv_b    = (const float*)d_in[3];
  const float* proj_w   = (const float*)d_in[4];
  const float* proj_b   = (const float*)d_in[5];
  const float* rpb_tab  = (const float*)d_in[6];
  const int*   rpb_idx  = (const int*)d_in[7];
  float* out = (float*)d_out;

  short* wqkv  = (short*)d_ws;                  // 196608 shorts
  short* wproj = wqkv + 768 * 256;              // 65536 shorts
  float* rpbT  = (float*)(wproj + 256 * 256);   // 32768 floats
  float* maskT = rpbT + 8 * 64 * 64;            // 262144 floats

  int total = 768 * 256 + 256 * 256 + 8 * 64 * 64 + 64 * 64 * 64;
  preconv_kernel<<<(total + 255) / 256, 256, 0, stream>>>(
      qkv_w, proj_w, rpb_tab, rpb_idx, mask, wqkv, wproj, rpbT, maskT);

  hipFuncSetAttribute((const void*)fused_attn,
                      hipFuncAttributeMaxDynamicSharedMemorySize, 65536);
  int B = in_sizes[0] / (TOK * CDIM);  // 2048
  fused_attn<<<B, 512, 65536, stream>>>(x, qkv_b, proj_b, wqkv, wproj,
                                        rpbT, maskT, out);
}

// Round 3
// 286.818 us; speedup vs baseline: 1.8071x; 1.8071x over previous
//
#include <hip/hip_runtime.h>
#include <hip/hip_bf16.h>

// WindowAttentionRPB fused kernel v3, MI355X gfx950.
// 1 block = 1 window, 512 threads = 8 waves = 8 heads.
// LDS 80K (= 160K/2 -> 2 blocks/CU):
//   [0,16K)   x half-buffer [64][128] bf16 (staged twice, K-halves)
//   [16K,80K) per-wave 8K scratch: sub0 (q -> vT), sub1 (k -> P chunks)
//   [16K,48K) attn-out [64][256] bf16 (after post-PV barrier, overlays w0-3)
// __launch_bounds__(512,2): 2nd arg = min BLOCKS/CU (CUDA semantics,
// confirmed by R1 VGPR=120 / R2 VGPR=64) -> 128-VGPR cap, no spills at ~124.

#define TOK 64
#define CDIM 256
#define SCR 16384
#define AT 16384

typedef __attribute__((ext_vector_type(8))) short short8;
typedef __attribute__((ext_vector_type(4))) float f32x4;
typedef __attribute__((ext_vector_type(4))) float float4_t;

__device__ __forceinline__ short f2bf(float f) {
  union { float f; unsigned u; } v; v.f = f;
  unsigned r = v.u + 0x7FFFu + ((v.u >> 16) & 1u);
  return (short)(r >> 16);
}

// swizzled byte address into a row-major [64][256] bf16 LDS region (512B rows)
__device__ __forceinline__ int rm_addr(int base, int row, int col) {
  return base + row * 512 + ((col * 2) ^ ((row & 7) << 4));
}
// x half-buffer: [64][128] bf16, 256B rows
__device__ __forceinline__ int xaddr(int row, int col) {
  return row * 256 + ((col * 2) ^ ((row & 7) << 4));
}

__global__ void preconv_kernel(const float* __restrict__ qkv_w,
                               const float* __restrict__ proj_w,
                               const float* __restrict__ rpb_table,
                               const int* __restrict__ rpb_index,
                               const float* __restrict__ mask,
                               short* __restrict__ wqkv,
                               short* __restrict__ wproj,
                               float* __restrict__ rpbT,
                               float* __restrict__ maskT) {
  int idx = blockIdx.x * blockDim.x + threadIdx.x;
  const float scale = 0.17677669529663687f; // 1/sqrt(32), folded into Wq
  const int NW1 = 768 * 256;
  const int NW2 = NW1 + 256 * 256;
  const int NW3 = NW2 + 8 * 64 * 64;
  const int NW4 = NW3 + 64 * 64 * 64;
  if (idx < NW1) {
    float v = qkv_w[idx];
    if (idx < 256 * 256) v *= scale;
    wqkv[idx] = f2bf(v);
  } else if (idx < NW2) {
    int i = idx - NW1;
    wproj[i] = f2bf(proj_w[i]);
  } else if (idx < NW3) {
    int i = idx - NW2;             // [h][qtok][ll*4+ni]
    int h = i >> 12;
    int pos = i & 4095;
    int qtok = pos >> 6;
    int t = pos & 63;
    int llv = t >> 2, ni = t & 3;
    int kt = ni * 16 + llv;
    rpbT[i] = rpb_table[rpb_index[qtok * 64 + kt] * 8 + h];
  } else if (idx < NW4) {
    int i = idx - NW3;             // [win][qtok][ll*4+ni]
    int win = i >> 12;
    int pos = i & 4095;
    int qtok = pos >> 6;
    int t = pos & 63;
    int llv = t >> 2, ni = t & 3;
    int kt = ni * 16 + llv;
    maskT[i] = mask[win * 4096 + qtok * 64 + kt];
  }
}

__global__ void __launch_bounds__(512, 2) fused_attn(
    const float* __restrict__ x, const float* __restrict__ qkv_b,
    const float* __restrict__ proj_b,
    const short* __restrict__ wqkv, const short* __restrict__ wproj,
    const float* __restrict__ rpbT, const float* __restrict__ maskT,
    float* __restrict__ out) {
  extern __shared__ char smem[];
  const int b = blockIdx.x;
  const int tid = threadIdx.x;
  const int w = tid >> 6;      // wave = head
  const int lane = tid & 63;
  const int lg = lane >> 4;    // lane group 0..3
  const int ll = lane & 15;
  const float scale = 0.17677669529663687f;
  const int S0 = SCR + w * 8192, S1 = S0 + 4096;

  // ---- QKV GEMM over two K-halves, x staged as [64][128] bf16 each half
  f32x4 acc[4][6] = {};
  for (int half = 0; half < 2; ++half) {
    {
      const int row = tid >> 3;
      const int c0 = (tid & 7) * 16;
      const float4_t* src = reinterpret_cast<const float4_t*>(
          x + (size_t)b * TOK * CDIM + row * CDIM + half * 128 + c0);
      float4_t f0 = src[0], f1 = src[1];
      short8 s;
      s[0] = f2bf(f0[0]); s[1] = f2bf(f0[1]); s[2] = f2bf(f0[2]); s[3] = f2bf(f0[3]);
      s[4] = f2bf(f1[0]); s[5] = f2bf(f1[1]); s[6] = f2bf(f1[2]); s[7] = f2bf(f1[3]);
      *reinterpret_cast<short8*>(smem + xaddr(row, c0)) = s;
      float4_t f2 = src[2], f3 = src[3];
      short8 t;
      t[0] = f2bf(f2[0]); t[1] = f2bf(f2[1]); t[2] = f2bf(f2[2]); t[3] = f2bf(f2[3]);
      t[4] = f2bf(f3[0]); t[5] = f2bf(f3[1]); t[6] = f2bf(f3[2]); t[7] = f2bf(f3[3]);
      *reinterpret_cast<short8*>(smem + xaddr(row, c0 + 8)) = t;
    }
    __syncthreads();
    for (int ks = 0; ks < 4; ++ks) {
      int k0 = ks * 32;
      short8 a[4];
      for (int mi = 0; mi < 4; ++mi)
        a[mi] = *reinterpret_cast<const short8*>(
            smem + xaddr(ll + 16 * mi, k0 + lg * 8));
      for (int j = 0; j < 6; ++j) {
        int s = j >> 1, hf = j & 1;
        int c = s * 256 + w * 32 + hf * 16 + ll;
        short8 bb = *reinterpret_cast<const short8*>(
            wqkv + c * 256 + half * 128 + k0 + lg * 8);
        for (int mi = 0; mi < 4; ++mi)
          acc[mi][j] = __builtin_amdgcn_mfma_f32_16x16x32_bf16(a[mi], bb, acc[mi][j], 0, 0, 0);
      }
    }
    if (half == 0) __syncthreads();  // all reads of half-0 done before restage
  }
  // From here: everything is wave-private scratch until the post-PV barrier.

  // ---- q -> sub0, k -> sub1  ([64 tok][32 d] bf16, swz (tok&3)<<4)
  for (int j = 0; j < 4; ++j) {
    int s = j >> 1, hf = j & 1;
    int c = s * 256 + w * 32 + hf * 16 + ll;
    float bias = qkv_b[c];
    if (s == 0) bias *= scale;
    int base = (s == 0) ? S0 : S1;
    int dl2 = (hf * 16 + ll) * 2;
    for (int mi = 0; mi < 4; ++mi)
      for (int r = 0; r < 4; ++r) {
        int tok = lg * 4 + r + 16 * mi;
        *reinterpret_cast<short*>(smem + base + tok * 64 + (dl2 ^ ((tok & 3) << 4))) =
            f2bf(acc[mi][j][r] + bias);
      }
  }
  // ---- read Q/K fragments
  short8 aq[4], bk[4];
  for (int mi = 0; mi < 4; ++mi)
    aq[mi] = *reinterpret_cast<const short8*>(
        smem + S0 + (ll + 16 * mi) * 64 + ((lg * 16) ^ (((ll + 16 * mi) & 3) << 4)));
  for (int ni = 0; ni < 4; ++ni)
    bk[ni] = *reinterpret_cast<const short8*>(
        smem + S1 + (ll + 16 * ni) * 64 + ((lg * 16) ^ (((ll + 16 * ni) & 3) << 4)));

  // ---- vT -> sub0 (overlays q; q frags already in regs). [32 d][64 tok]
  for (int hf = 0; hf < 2; ++hf) {
    int c = 2 * 256 + w * 32 + hf * 16 + ll;
    float bias = qkv_b[c];
    int d = hf * 16 + ll;
    for (int mi = 0; mi < 4; ++mi)
      for (int rp = 0; rp < 2; ++rp) {
        int tok0 = lg * 4 + rp * 2 + 16 * mi;
        unsigned u = (unsigned)(unsigned short)f2bf(acc[mi][4 + hf][2 * rp] + bias)
                   | ((unsigned)(unsigned short)f2bf(acc[mi][4 + hf][2 * rp + 1] + bias) << 16);
        *reinterpret_cast<unsigned*>(smem + S0 + d * 128 + ((tok0 * 2) ^ ((d & 7) << 4))) = u;
      }
  }

  // ---- S = q_scaled @ k^T + rpb + mask
  f32x4 sa[4][4];
  {
    f32x4 z{0.0f, 0.0f, 0.0f, 0.0f};
    for (int mi = 0; mi < 4; ++mi)
      for (int ni = 0; ni < 4; ++ni)
        sa[mi][ni] = __builtin_amdgcn_mfma_f32_16x16x32_bf16(aq[mi], bk[ni], z, 0, 0, 0);
    const float4_t* rpT4 = reinterpret_cast<const float4_t*>(rpbT) + w * 1024;
    const float4_t* mkT4 = reinterpret_cast<const float4_t*>(maskT) + (b & 63) * 1024;
    for (int mi = 0; mi < 4; ++mi)
      for (int r = 0; r < 4; ++r) {
        int qtok = lg * 4 + r + 16 * mi;
        float4_t f = rpT4[qtok * 16 + ll];
        float4_t g = mkT4[qtok * 16 + ll];
        for (int ni = 0; ni < 4; ++ni)
          sa[mi][ni][r] += f[ni] + g[ni];
      }
  }

  // ---- softmax over cols (row lives in one 16-lane group)
  float rinv[4][4];
  for (int mi = 0; mi < 4; ++mi)
    for (int r = 0; r < 4; ++r) {
      float m = sa[mi][0][r];
      for (int ni = 1; ni < 4; ++ni) m = fmaxf(m, sa[mi][ni][r]);
      for (int d = 1; d < 16; d <<= 1) m = fmaxf(m, __shfl_xor(m, d));
      float sum = 0.f;
      for (int ni = 0; ni < 4; ++ni) {
        float e = __expf(sa[mi][ni][r] - m);
        sa[mi][ni][r] = e;
        sum += e;
      }
      for (int d = 1; d < 16; d <<= 1) sum += __shfl_xor(sum, d);
      rinv[mi][r] = 1.0f / sum;
    }

  // ---- PV in two 32-kt chunks through sub1 (overlays k)
  f32x4 oa[4][2] = {};
  for (int ks = 0; ks < 2; ++ks) {
    for (int mi = 0; mi < 4; ++mi)
      for (int nio = 0; nio < 2; ++nio) {
        int ni = 2 * ks + nio;
        int ktl2 = (nio * 16 + ll) * 2;
        for (int r = 0; r < 4; ++r) {
          int qtok = lg * 4 + r + 16 * mi;
          *reinterpret_cast<short*>(smem + S1 + qtok * 64 + (ktl2 ^ ((qtok & 3) << 4))) =
              f2bf(sa[mi][ni][r]);
        }
      }
    short8 ap[4], bv[2];
    for (int mi = 0; mi < 4; ++mi)
      ap[mi] = *reinterpret_cast<const short8*>(
          smem + S1 + (ll + 16 * mi) * 64 + ((lg * 16) ^ (((ll + 16 * mi) & 3) << 4)));
    for (int njf = 0; njf < 2; ++njf) {
      int d = njf * 16 + ll;
      bv[njf] = *reinterpret_cast<const short8*>(
          smem + S0 + d * 128 + (((ks * 32 + lg * 8) * 2) ^ ((d & 7) << 4)));
    }
    for (int mi = 0; mi < 4; ++mi)
      for (int njf = 0; njf < 2; ++njf)
        oa[mi][njf] = __builtin_amdgcn_mfma_f32_16x16x32_bf16(ap[mi], bv[njf], oa[mi][njf], 0, 0, 0);
  }

  __syncthreads();  // all scratch reads done -> attn region writable

  // ---- normalize rows, write attn output (bf16) into AT [64][256]
  for (int mi = 0; mi < 4; ++mi)
    for (int nj = 0; nj < 2; ++nj)
      for (int r = 0; r < 4; ++r) {
        int row = lg * 4 + r + 16 * mi;
        float v = oa[mi][nj][r] * rinv[mi][r];
        *reinterpret_cast<short*>(smem + rm_addr(AT, row, w * 32 + nj * 16 + ll)) = f2bf(v);
      }
  __syncthreads();

  // ---- proj GEMM: out[64][256] = attn[64][256] @ Wp^T + bias
  f32x4 pa[4][2] = {};
  for (int ks = 0; ks < 8; ++ks) {
    int k0 = ks * 32;
    short8 a[4];
    for (int mi = 0; mi < 4; ++mi)
      a[mi] = *reinterpret_cast<const short8*>(
          smem + rm_addr(AT, ll + 16 * mi, k0 + lg * 8));
    for (int nj = 0; nj < 2; ++nj) {
      int c = w * 32 + nj * 16 + ll;
      short8 bb = *reinterpret_cast<const short8*>(wproj + c * 256 + k0 + lg * 8);
      for (int mi = 0; mi < 4; ++mi)
        pa[mi][nj] = __builtin_amdgcn_mfma_f32_16x16x32_bf16(a[mi], bb, pa[mi][nj], 0, 0, 0);
    }
  }
  float* outp = out + (size_t)b * TOK * CDIM;
  for (int nj = 0; nj < 2; ++nj) {
    int c = w * 32 + nj * 16 + ll;
    float bias = proj_b[c];
    for (int mi = 0; mi < 4; ++mi)
      for (int r = 0; r < 4; ++r) {
        int row = lg * 4 + r + 16 * mi;
        outp[row * 256 + c] = pa[mi][nj][r] + bias;
      }
  }
}

extern "C" void kernel_launch(void* const* d_in, const int* in_sizes, int n_in,
                              void* d_out, int out_size, void* d_ws, size_t ws_size,
                              hipStream_t stream) {
  const float* x        = (const float*)d_in[0];
  const float* mask     = (const float*)d_in[1];
  const float* qkv_w    = (const float*)d_in[2];
  const float* qkv_b    = (const float*)d_in[3];
  const float* proj_w   = (const float*)d_in[4];
  const float* proj_b   = (const float*)d_in[5];
  const float* rpb_tab  = (const float*)d_in[6];
  const int*   rpb_idx  = (const int*)d_in[7];
  float* out = (float*)d_out;

  short* wqkv  = (short*)d_ws;                  // 196608 shorts
  short* wproj = wqkv + 768 * 256;              // 65536 shorts
  float* rpbT  = (float*)(wproj + 256 * 256);   // 32768 floats
  float* maskT = rpbT + 8 * 64 * 64;            // 262144 floats

  int total = 768 * 256 + 256 * 256 + 8 * 64 * 64 + 64 * 64 * 64;
  preconv_kernel<<<(total + 255) / 256, 256, 0, stream>>>(
      qkv_w, proj_w, rpb_tab, rpb_idx, mask, wqkv, wproj, rpbT, maskT);

  hipFuncSetAttribute((const void*)fused_attn,
                      hipFuncAttributeMaxDynamicSharedMemorySize, 81920);
  int B = in_sizes[0] / (TOK * CDIM);  // 2048
  fused_attn<<<B, 512, 81920, stream>>>(x, qkv_b, proj_b, wqkv, wproj,
                                        rpbT, maskT, out);
}